// Round 2
// baseline (730.860 us; speedup 1.0000x reference)
//
#include <hip/hip_runtime.h>
#include <hip/hip_bf16.h>
#include <stdint.h>

// MutualCrossAttention: B=8, C=64, H=W=64 -> T=4096 tokens. Inputs FP32, output FP32.
// dir A: Q=x1, K=V=x2 ; dir B: Q=x2, K=V=x1 ; out = outA + outB, layout [b][c][t].
// R14 = R12 skeleton (LDS K-staging, 8 waves = dir x pair x ks, 2 blk/CU, barrier
// lockstep — R13 proved free-run + global K is 1.7x WORSE) + V register prefetch:
// the 8 V-fragment loads of PV(j) are the only global loads consumed in the same
// phase they are issued (c-major 16x64B scatter, ~300cy L2). They are now issued
// right after S(j) in the PREVIOUS barrier gap into vpf[2][4] regs, so the
// barrier + wrst + loadst + pf-reads cover their latency and PV is pure reg-MFMA.
//   - S^T composition (A=K,B=Q then A=V,B=P^T) proved in R3-R5; P^T C/D layout
//     gives 4 consecutive tokens/lane -> b64 pbuf write, b128 read, stride-72.
//   - lp is one scalar per lane (q = l16 column), butterflied over quads.
//   - O^T epilogue: row=c, col=q -> scalar f32 stores coalesced over l16.
// ws: [0,8MB) xt bf16 token-major {x1,x2} PRE-SCALED by sqrt(log2(e)/8);
//     [8MB,16MB) vt bf16 c-major {x1,x2} unscaled.

#define TT 4096
#define CC 64
#define NB 8

typedef float f32x4 __attribute__((ext_vector_type(4)));
typedef float f32x4a __attribute__((ext_vector_type(4), may_alias));
typedef short s16x8 __attribute__((ext_vector_type(8)));
typedef unsigned int u32x2a __attribute__((ext_vector_type(2), may_alias));
typedef unsigned int u32x4a __attribute__((ext_vector_type(4), may_alias));
typedef float f32a __attribute__((may_alias));

static __device__ __forceinline__ unsigned fbits(float x) { return __float_as_uint(x); }
static __device__ __forceinline__ ushort bf16of(float v) {
    return (ushort)((fbits(v) + 0x8000u) >> 16);
}
static __device__ __forceinline__ unsigned pack2(float a, float b) {
    return __builtin_amdgcn_perm(fbits(b) + 0x8000u, fbits(a) + 0x8000u, 0x07060302u);
}
static __device__ __forceinline__ s16x8 load_frag(const void* p) {
    u32x4a t = *(const u32x4a*)p;
    return __builtin_bit_cast(s16x8, t);
}

#define SQC1 0.4246609177f  // sqrt(log2(e)/8), applied to xt on both Q and K sides

__global__ void prep_k(const float* __restrict__ x1, const float* __restrict__ x2,
                       ushort* __restrict__ xt, ushort* __restrict__ vt) {
    const int inp = blockIdx.z, b = blockIdx.y, t0 = blockIdx.x * 64;
    const float* src = (inp == 0 ? x1 : x2) + (size_t)b * CC * TT;
    const size_t plane = (size_t)TT * CC;
    ushort* xd = xt + (size_t)(inp * NB + b) * plane;
    ushort* vd = vt + (size_t)(inp * NB + b) * plane;
    __shared__ ushort lds[64][72];
    const int tid = threadIdx.x;
    const int c  = tid >> 2;
    const int tg = tid & 3;
    const float* srow = src + (size_t)c * TT + t0 + tg * 16;
    unsigned hw[8];
#pragma unroll
    for (int i = 0; i < 4; ++i) {
        f32x4a v = *(const f32x4a*)(srow + i * 4);
        hw[2 * i]     = pack2(v[0], v[1]);
        hw[2 * i + 1] = pack2(v[2], v[3]);
#pragma unroll
        for (int k = 0; k < 4; ++k) lds[tg * 16 + i * 4 + k][c] = bf16of(v[k] * SQC1);
    }
    ushort* vrow = vd + (size_t)c * TT + t0 + tg * 16;
    u32x4a w0 = {hw[0], hw[1], hw[2], hw[3]};
    u32x4a w1 = {hw[4], hw[5], hw[6], hw[7]};
    *(u32x4a*)(vrow) = w0;
    *(u32x4a*)(vrow + 8) = w1;
    __syncthreads();
#pragma unroll
    for (int pass = 0; pass < 2; ++pass) {
        const int t  = (tid >> 3) + pass * 32;
        const int c8 = (tid & 7) * 8;
        u32x4a w = *(const u32x4a*)&lds[t][c8];
        *(u32x4a*)(xd + (size_t)(t0 + t) * CC + c8) = w;
    }
}

// grid = 512 blocks (qt 0..63 x b 0..7), 512 threads = 8 waves.
// wave: dir = w&1, pair = (w>>1)&1, ks = w>>2 (2048-token half).
__global__ __launch_bounds__(512, 4)
void attn_fused_k(const ushort* __restrict__ xt, const ushort* __restrict__ vt,
                  float* __restrict__ out) {
    const int b    = blockIdx.x & 7;
    const int qt   = blockIdx.x >> 3;
    const int tid  = threadIdx.x;
    const int wave = tid >> 6;
    const int lane = tid & 63;
    const int quad = lane >> 4;
    const int l16  = lane & 15;
    const int dir  = wave & 1;
    const int pair = (wave >> 1) & 1;
    const int ks   = wave >> 2;
    const int q0   = qt * 64 + pair * 32;

    const size_t plane = (size_t)TT * CC;
    const ushort* Qb = xt + (size_t)((dir == 0 ? 0 : NB) + b) * plane;  // token-major
    const ushort* Vb = vt + (size_t)((dir == 0 ? NB : 0) + b) * plane;  // c-major

    __shared__ __align__(16) ushort ktile[4][64][72];      // 36.9 KB
    __shared__ __align__(16) ushort pbuf[8][2][16][72];    // 36.9 KB (q rows, tok cols)
    __shared__ float lpx[8][2][16];                        // 1 KB
    f32a* xbuf = (f32a*)&pbuf[0][0][0][0];                 // 16 KB overlay, post-loop

    // staging role: tile sub = (sk,sd); 4 x 16B chunks per thread.
    const int sub = tid >> 7;
    const int sk  = sub >> 1;
    const int sd  = sub & 1;
    const int ch0 = tid & 127;
    const ushort* Ksrc = xt + (size_t)((sd == 0 ? NB : 0) + b) * plane;
    u32x4a st[4];

    auto loadst = [&](int j) {
        const ushort* g = Ksrc + (size_t)(sk * 32 + j) * 64 * CC;
#pragma unroll
        for (int i = 0; i < 4; ++i)
            st[i] = *(const u32x4a*)(g + (size_t)(ch0 + i * 128) * 8);
    };
    auto wrst = [&]() {
        unsigned* d = (unsigned*)&ktile[sub][0][0];
#pragma unroll
        for (int i = 0; i < 4; ++i) {
            const int c = ch0 + i * 128;
            *(u32x4a*)&d[(c >> 3) * 36 + (c & 7) * 4] = st[i];
        }
    };

    // Q b-frags: B[n=q=l16][k=c=quad*8+j], pre-scaled.
    s16x8 qf[2][2];
#pragma unroll
    for (int rb = 0; rb < 2; ++rb)
#pragma unroll
        for (int ch = 0; ch < 2; ++ch)
            qf[rb][ch] = load_frag(Qb + (size_t)(q0 + rb * 16 + l16) * CC + ch * 32 + quad * 8);

    f32x4 accO[2][4];  // O^T partial: row=c=quad*4+r (+ct*16), col=q=l16 (+rb*16)
#pragma unroll
    for (int rb = 0; rb < 2; ++rb)
#pragma unroll
        for (int ct = 0; ct < 4; ++ct) accO[rb][ct] = (f32x4){0.f, 0.f, 0.f, 0.f};
    float lp[2] = {0.f, 0.f};

    const ushort* vp  = Vb + (size_t)l16 * TT + quad * 8;
    const ushort* kfb = &ktile[ks * 2 + dir][0][0];

    // V register prefetch for PV(j): issued in the barrier gap BEFORE PV(j) runs.
    s16x8 vpf[2][4];
    auto prefV = [&](int j) {
        const int k0 = (ks * 32 + j) * 64;
#pragma unroll
        for (int ch2 = 0; ch2 < 2; ++ch2)
#pragma unroll
            for (int ct = 0; ct < 4; ++ct)
                vpf[ch2][ct] = load_frag(vp + (size_t)(ct * 16) * TT + k0 + ch2 * 32);
    };

    // S^T(j): A = K from staged ktile [m=tok=mt*16+l16][k=c], B = Q.
    // D[row=tok=quad*4+r (+mt*16)][col=q=l16] -> 4 consecutive tokens -> b64 P write.
    auto Sphase = [&]() {
#pragma unroll
        for (int mt = 0; mt < 4; ++mt) {
            const ushort* kr = kfb + (size_t)(mt * 16 + l16) * 72 + quad * 8;
            s16x8 kf0 = load_frag(kr);
            s16x8 kf1 = load_frag(kr + 32);
#pragma unroll
            for (int rb = 0; rb < 2; ++rb) {
                f32x4 s = (f32x4){0.f, 0.f, 0.f, 0.f};
                s = __builtin_amdgcn_mfma_f32_16x16x32_bf16(kf0, qf[rb][0], s, 0, 0, 0);
                s = __builtin_amdgcn_mfma_f32_16x16x32_bf16(kf1, qf[rb][1], s, 0, 0, 0);
                float p0 = __builtin_amdgcn_exp2f(s[0]);
                float p1 = __builtin_amdgcn_exp2f(s[1]);
                float p2 = __builtin_amdgcn_exp2f(s[2]);
                float p3 = __builtin_amdgcn_exp2f(s[3]);
                lp[rb] += (p0 + p1) + (p2 + p3);
                u32x2a w;
                w[0] = pack2(p0, p1);
                w[1] = pack2(p2, p3);
                *(u32x2a*)&pbuf[wave][rb][l16][mt * 16 + quad * 4] = w;
            }
        }
    };
    // PV(j): A = V (prefetched regs) [m=c=l16(+ct*16)][k=tok], B = P^T [n=q=l16][k=tok].
    auto PVphase = [&]() {
#pragma unroll
        for (int ch2 = 0; ch2 < 2; ++ch2) {
            s16x8 pf[2];
#pragma unroll
            for (int rb = 0; rb < 2; ++rb)
                pf[rb] = load_frag(&pbuf[wave][rb][l16][ch2 * 32 + quad * 8]);
#pragma unroll
            for (int ct = 0; ct < 4; ++ct) {
#pragma unroll
                for (int rb = 0; rb < 2; ++rb)
                    accO[rb][ct] = __builtin_amdgcn_mfma_f32_16x16x32_bf16(
                        vpf[ch2][ct], pf[rb], accO[rb][ct], 0, 0, 0);
            }
        }
    };

    // Pipeline: S(j) + prefV(j) in one barrier gap; wrst/loadst + PV(j-1) in the other.
    // vmcnt ordering per iter: st loads issue before vpf loads, so counted waits
    // never force-drain the younger prefetches.
    loadst(0);
    wrst();
    loadst(1);
    __syncthreads();
    Sphase();            // j = 0
    prefV(0);
#pragma unroll 1
    for (int j = 1; j < 32; ++j) {
        __syncthreads();           // all waves done reading ktile(j-1)
        wrst();                    // write ktile(j)
        if (j < 31) loadst(j + 1);
        PVphase();                 // PV(j-1): pure reg-MFMA, overlaps staging drain
        __syncthreads();           // ktile(j) visible
        Sphase();                  // S(j), overwrites pbuf AFTER PV consumed it
        prefV(j);                  // V(j) latency covered by next barrier gap
    }
    PVphase();           // PV(31)

    // Denominator: quads hold disjoint token subsets for col q=l16.
    float inv[2];
#pragma unroll
    for (int rb = 0; rb < 2; ++rb) {
        float l = lp[rb];
        l += __shfl_xor(l, 16);
        l += __shfl_xor(l, 32);
        lp[rb] = l;
        if (lane < 16) lpx[wave][rb][l16] = l;
    }
    __syncthreads();  // pbuf dead -> xbuf overlay safe; lpx visible
#pragma unroll
    for (int rb = 0; rb < 2; ++rb)
        inv[rb] = __builtin_amdgcn_rcpf(lp[rb] + lpx[wave ^ 4][rb][l16]);

    // 4-phase merge over g = (ks,dir) into xbuf[pair]; g==0 stores.
    const int g = (ks << 1) | dir;
#pragma unroll 1
    for (int ph = 3; ph >= 1; --ph) {
        if (g == ph) {
#pragma unroll
            for (int rb = 0; rb < 2; ++rb)
#pragma unroll
                for (int ct = 0; ct < 4; ++ct)
#pragma unroll
                    for (int r = 0; r < 4; ++r) {
                        const int slot = (pair * 32 + rb * 16 + ct * 4 + r) * 64 + lane;
                        float v = accO[rb][ct][r] * inv[rb];
                        if (ph == 3) xbuf[slot] = v;
                        else xbuf[slot] += v;
                    }
        }
        __syncthreads();
    }
    if (g == 0) {
        float* ob = out + (size_t)b * plane;
#pragma unroll
        for (int rb = 0; rb < 2; ++rb)
#pragma unroll
            for (int ct = 0; ct < 4; ++ct)
#pragma unroll
                for (int r = 0; r < 4; ++r) {
                    float v = accO[rb][ct][r] * inv[rb] +
                              xbuf[(pair * 32 + rb * 16 + ct * 4 + r) * 64 + lane];
                    // out[c = ct*16+quad*4+r][t = q0+rb*16+l16]: coalesced over l16
                    ob[(size_t)(ct * 16 + quad * 4 + r) * TT + q0 + rb * 16 + l16] = v;
                }
    }
}

extern "C" void kernel_launch(void* const* d_in, const int* in_sizes, int n_in,
                              void* d_out, int out_size, void* d_ws, size_t ws_size,
                              hipStream_t stream) {
    const float* x1 = (const float*)d_in[0];
    const float* x2 = (const float*)d_in[1];
    ushort* xt = (ushort*)d_ws;                              // 8 MB
    ushort* vt = (ushort*)d_ws + (size_t)2 * NB * TT * CC;   // 8 MB

    hipLaunchKernelGGL(prep_k, dim3(TT / 64, NB, 2), dim3(256), 0, stream, x1, x2, xt, vt);
    hipLaunchKernelGGL(attn_fused_k, dim3(64 * NB), dim3(512), 0, stream,
                       xt, vt, (float*)d_out);
}

// Round 3
// 355.852 us; speedup vs baseline: 2.0538x; 2.0538x over previous
//
#include <hip/hip_runtime.h>
#include <hip/hip_bf16.h>
#include <stdint.h>

// MutualCrossAttention: B=8, C=64, H=W=64 -> T=4096 tokens. Inputs FP32, output FP32.
// dir A: Q=x1, K=V=x2 ; dir B: Q=x2, K=V=x1 ; out = outA + outB, layout [b][c][t].
// R15 = R12 skeleton (LDS K-staging, 8 waves = dir x pair x ks, 2 blk/CU, barrier
// lockstep — R13 proved free-run+global-K is 1.7x worse) + V register prefetch in
// EIGHT NAMED s16x8 REGISTERS (R14 used a [2][4] array -> compiler spilled it to
// scratch: WRITE_SIZE 17MB->1.78GB, 4.3x regression; named scalars cannot be
// aggregate-spilled). prefV(j) issues right after the 2nd barrier so the whole
// Sphase covers the ~300cy L2 latency of the 8 c-major V loads; PVphase is pure
// reg-MFMA and overlaps the staging drain in the other barrier gap.
//   - S^T composition (A=K,B=Q then A=V,B=P^T) proved in R3-R5; P^T C/D layout
//     gives 4 consecutive tokens/lane -> b64 pbuf write, b128 read, stride-72.
//   - lp is one scalar per lane (q = l16 column), butterflied over quads.
//   - O^T epilogue: row=c, col=q -> scalar f32 stores coalesced over l16.
// ws: [0,8MB) xt bf16 token-major {x1,x2} PRE-SCALED by sqrt(log2(e)/8);
//     [8MB,16MB) vt bf16 c-major {x1,x2} unscaled.

#define TT 4096
#define CC 64
#define NB 8

typedef float f32x4 __attribute__((ext_vector_type(4)));
typedef float f32x4a __attribute__((ext_vector_type(4), may_alias));
typedef short s16x8 __attribute__((ext_vector_type(8)));
typedef unsigned int u32x2a __attribute__((ext_vector_type(2), may_alias));
typedef unsigned int u32x4a __attribute__((ext_vector_type(4), may_alias));
typedef float f32a __attribute__((may_alias));

static __device__ __forceinline__ unsigned fbits(float x) { return __float_as_uint(x); }
static __device__ __forceinline__ ushort bf16of(float v) {
    return (ushort)((fbits(v) + 0x8000u) >> 16);
}
static __device__ __forceinline__ unsigned pack2(float a, float b) {
    return __builtin_amdgcn_perm(fbits(b) + 0x8000u, fbits(a) + 0x8000u, 0x07060302u);
}
static __device__ __forceinline__ s16x8 load_frag(const void* p) {
    u32x4a t = *(const u32x4a*)p;
    return __builtin_bit_cast(s16x8, t);
}

#define SQC1 0.4246609177f  // sqrt(log2(e)/8), applied to xt on both Q and K sides

__global__ void prep_k(const float* __restrict__ x1, const float* __restrict__ x2,
                       ushort* __restrict__ xt, ushort* __restrict__ vt) {
    const int inp = blockIdx.z, b = blockIdx.y, t0 = blockIdx.x * 64;
    const float* src = (inp == 0 ? x1 : x2) + (size_t)b * CC * TT;
    const size_t plane = (size_t)TT * CC;
    ushort* xd = xt + (size_t)(inp * NB + b) * plane;
    ushort* vd = vt + (size_t)(inp * NB + b) * plane;
    __shared__ ushort lds[64][72];
    const int tid = threadIdx.x;
    const int c  = tid >> 2;
    const int tg = tid & 3;
    const float* srow = src + (size_t)c * TT + t0 + tg * 16;
    unsigned hw[8];
#pragma unroll
    for (int i = 0; i < 4; ++i) {
        f32x4a v = *(const f32x4a*)(srow + i * 4);
        hw[2 * i]     = pack2(v[0], v[1]);
        hw[2 * i + 1] = pack2(v[2], v[3]);
#pragma unroll
        for (int k = 0; k < 4; ++k) lds[tg * 16 + i * 4 + k][c] = bf16of(v[k] * SQC1);
    }
    ushort* vrow = vd + (size_t)c * TT + t0 + tg * 16;
    u32x4a w0 = {hw[0], hw[1], hw[2], hw[3]};
    u32x4a w1 = {hw[4], hw[5], hw[6], hw[7]};
    *(u32x4a*)(vrow) = w0;
    *(u32x4a*)(vrow + 8) = w1;
    __syncthreads();
#pragma unroll
    for (int pass = 0; pass < 2; ++pass) {
        const int t  = (tid >> 3) + pass * 32;
        const int c8 = (tid & 7) * 8;
        u32x4a w = *(const u32x4a*)&lds[t][c8];
        *(u32x4a*)(xd + (size_t)(t0 + t) * CC + c8) = w;
    }
}

// grid = 512 blocks (qt 0..63 x b 0..7), 512 threads = 8 waves.
// wave: dir = w&1, pair = (w>>1)&1, ks = w>>2 (2048-token half).
__global__ __launch_bounds__(512, 4)
void attn_fused_k(const ushort* __restrict__ xt, const ushort* __restrict__ vt,
                  float* __restrict__ out) {
    const int b    = blockIdx.x & 7;
    const int qt   = blockIdx.x >> 3;
    const int tid  = threadIdx.x;
    const int wave = tid >> 6;
    const int lane = tid & 63;
    const int quad = lane >> 4;
    const int l16  = lane & 15;
    const int dir  = wave & 1;
    const int pair = (wave >> 1) & 1;
    const int ks   = wave >> 2;
    const int q0   = qt * 64 + pair * 32;

    const size_t plane = (size_t)TT * CC;
    const ushort* Qb = xt + (size_t)((dir == 0 ? 0 : NB) + b) * plane;  // token-major
    const ushort* Vb = vt + (size_t)((dir == 0 ? NB : 0) + b) * plane;  // c-major

    __shared__ __align__(16) ushort ktile[4][64][72];      // 36.9 KB
    __shared__ __align__(16) ushort pbuf[8][2][16][72];    // 36.9 KB (q rows, tok cols)
    __shared__ float lpx[8][2][16];                        // 1 KB
    f32a* xbuf = (f32a*)&pbuf[0][0][0][0];                 // 16 KB overlay, post-loop

    // staging role: tile sub = (sk,sd); 4 x 16B chunks per thread.
    const int sub = tid >> 7;
    const int sk  = sub >> 1;
    const int sd  = sub & 1;
    const int ch0 = tid & 127;
    const ushort* Ksrc = xt + (size_t)((sd == 0 ? NB : 0) + b) * plane;
    u32x4a st[4];

    auto loadst = [&](int j) {
        const ushort* g = Ksrc + (size_t)(sk * 32 + j) * 64 * CC;
#pragma unroll
        for (int i = 0; i < 4; ++i)
            st[i] = *(const u32x4a*)(g + (size_t)(ch0 + i * 128) * 8);
    };
    auto wrst = [&]() {
        unsigned* d = (unsigned*)&ktile[sub][0][0];
#pragma unroll
        for (int i = 0; i < 4; ++i) {
            const int c = ch0 + i * 128;
            *(u32x4a*)&d[(c >> 3) * 36 + (c & 7) * 4] = st[i];
        }
    };

    // Q b-frags: B[n=q=l16][k=c=quad*8+j], pre-scaled.
    s16x8 qf[2][2];
#pragma unroll
    for (int rb = 0; rb < 2; ++rb)
#pragma unroll
        for (int ch = 0; ch < 2; ++ch)
            qf[rb][ch] = load_frag(Qb + (size_t)(q0 + rb * 16 + l16) * CC + ch * 32 + quad * 8);

    f32x4 accO[2][4];  // O^T partial: row=c=quad*4+r (+ct*16), col=q=l16 (+rb*16)
#pragma unroll
    for (int rb = 0; rb < 2; ++rb)
#pragma unroll
        for (int ct = 0; ct < 4; ++ct) accO[rb][ct] = (f32x4){0.f, 0.f, 0.f, 0.f};
    float lp[2] = {0.f, 0.f};

    const ushort* vp  = Vb + (size_t)l16 * TT + quad * 8;
    const ushort* kfb = &ktile[ks * 2 + dir][0][0];

    // V register prefetch for PV(j): EIGHT NAMED regs (vA* = ch2 0, vB* = ch2 1),
    // issued right after the 2nd barrier so Sphase covers the L2 latency.
    s16x8 vA0, vA1, vA2, vA3, vB0, vB1, vB2, vB3;
    auto prefV = [&](int j) {
        const ushort* p0 = vp + (size_t)(ks * 32 + j) * 64;
        vA0 = load_frag(p0 + (size_t)( 0) * TT);
        vA1 = load_frag(p0 + (size_t)(16) * TT);
        vA2 = load_frag(p0 + (size_t)(32) * TT);
        vA3 = load_frag(p0 + (size_t)(48) * TT);
        vB0 = load_frag(p0 + (size_t)( 0) * TT + 32);
        vB1 = load_frag(p0 + (size_t)(16) * TT + 32);
        vB2 = load_frag(p0 + (size_t)(32) * TT + 32);
        vB3 = load_frag(p0 + (size_t)(48) * TT + 32);
    };

    // S^T(j): A = K from staged ktile [m=tok=mt*16+l16][k=c], B = Q.
    // D[row=tok=quad*4+r (+mt*16)][col=q=l16] -> 4 consecutive tokens -> b64 P write.
    auto Sphase = [&]() {
#pragma unroll
        for (int mt = 0; mt < 4; ++mt) {
            const ushort* kr = kfb + (size_t)(mt * 16 + l16) * 72 + quad * 8;
            s16x8 kf0 = load_frag(kr);
            s16x8 kf1 = load_frag(kr + 32);
#pragma unroll
            for (int rb = 0; rb < 2; ++rb) {
                f32x4 s = (f32x4){0.f, 0.f, 0.f, 0.f};
                s = __builtin_amdgcn_mfma_f32_16x16x32_bf16(kf0, qf[rb][0], s, 0, 0, 0);
                s = __builtin_amdgcn_mfma_f32_16x16x32_bf16(kf1, qf[rb][1], s, 0, 0, 0);
                float p0 = __builtin_amdgcn_exp2f(s[0]);
                float p1 = __builtin_amdgcn_exp2f(s[1]);
                float p2 = __builtin_amdgcn_exp2f(s[2]);
                float p3 = __builtin_amdgcn_exp2f(s[3]);
                lp[rb] += (p0 + p1) + (p2 + p3);
                u32x2a w;
                w[0] = pack2(p0, p1);
                w[1] = pack2(p2, p3);
                *(u32x2a*)&pbuf[wave][rb][l16][mt * 16 + quad * 4] = w;
            }
        }
    };
    // PV(j): A = V (prefetched named regs) [m=c=l16(+ct*16)][k=tok],
    //        B = P^T [n=q=l16][k=tok] (b128 LDS). Pure reg-MFMA otherwise.
    auto PVphase = [&]() {
        s16x8 pf0a = load_frag(&pbuf[wave][0][l16][quad * 8]);
        s16x8 pf1a = load_frag(&pbuf[wave][1][l16][quad * 8]);
        accO[0][0] = __builtin_amdgcn_mfma_f32_16x16x32_bf16(vA0, pf0a, accO[0][0], 0, 0, 0);
        accO[1][0] = __builtin_amdgcn_mfma_f32_16x16x32_bf16(vA0, pf1a, accO[1][0], 0, 0, 0);
        accO[0][1] = __builtin_amdgcn_mfma_f32_16x16x32_bf16(vA1, pf0a, accO[0][1], 0, 0, 0);
        accO[1][1] = __builtin_amdgcn_mfma_f32_16x16x32_bf16(vA1, pf1a, accO[1][1], 0, 0, 0);
        accO[0][2] = __builtin_amdgcn_mfma_f32_16x16x32_bf16(vA2, pf0a, accO[0][2], 0, 0, 0);
        accO[1][2] = __builtin_amdgcn_mfma_f32_16x16x32_bf16(vA2, pf1a, accO[1][2], 0, 0, 0);
        accO[0][3] = __builtin_amdgcn_mfma_f32_16x16x32_bf16(vA3, pf0a, accO[0][3], 0, 0, 0);
        accO[1][3] = __builtin_amdgcn_mfma_f32_16x16x32_bf16(vA3, pf1a, accO[1][3], 0, 0, 0);
        s16x8 pf0b = load_frag(&pbuf[wave][0][l16][32 + quad * 8]);
        s16x8 pf1b = load_frag(&pbuf[wave][1][l16][32 + quad * 8]);
        accO[0][0] = __builtin_amdgcn_mfma_f32_16x16x32_bf16(vB0, pf0b, accO[0][0], 0, 0, 0);
        accO[1][0] = __builtin_amdgcn_mfma_f32_16x16x32_bf16(vB0, pf1b, accO[1][0], 0, 0, 0);
        accO[0][1] = __builtin_amdgcn_mfma_f32_16x16x32_bf16(vB1, pf0b, accO[0][1], 0, 0, 0);
        accO[1][1] = __builtin_amdgcn_mfma_f32_16x16x32_bf16(vB1, pf1b, accO[1][1], 0, 0, 0);
        accO[0][2] = __builtin_amdgcn_mfma_f32_16x16x32_bf16(vB2, pf0b, accO[0][2], 0, 0, 0);
        accO[1][2] = __builtin_amdgcn_mfma_f32_16x16x32_bf16(vB2, pf1b, accO[1][2], 0, 0, 0);
        accO[0][3] = __builtin_amdgcn_mfma_f32_16x16x32_bf16(vB3, pf0b, accO[0][3], 0, 0, 0);
        accO[1][3] = __builtin_amdgcn_mfma_f32_16x16x32_bf16(vB3, pf1b, accO[1][3], 0, 0, 0);
    };

    // Pipeline per iter: [B1] wrst + loadst(j+1) + PV(j-1) [B2] prefV(j) + S(j).
    // prefV right after B2 -> the whole Sphase covers the 8 V loads; B1 of the
    // next iteration drains them (vmcnt(0)) after they are long complete.
    loadst(0);
    wrst();
    loadst(1);
    __syncthreads();
    prefV(0);
    Sphase();            // j = 0
#pragma unroll 1
    for (int j = 1; j < 32; ++j) {
        __syncthreads();           // B1: all waves done reading ktile(j-1); V(j-1) drained
        wrst();                    // write ktile(j)
        if (j < 31) loadst(j + 1);
        PVphase();                 // PV(j-1): pure reg-MFMA, overlaps staging drain
        __syncthreads();           // B2: ktile(j) visible
        prefV(j);                  // V(j) loads covered by Sphase(j)
        Sphase();                  // S(j), overwrites pbuf AFTER PV consumed it
    }
    PVphase();           // PV(31)

    // Denominator: quads hold disjoint token subsets for col q=l16.
    float inv[2];
#pragma unroll
    for (int rb = 0; rb < 2; ++rb) {
        float l = lp[rb];
        l += __shfl_xor(l, 16);
        l += __shfl_xor(l, 32);
        lp[rb] = l;
        if (lane < 16) lpx[wave][rb][l16] = l;
    }
    __syncthreads();  // pbuf dead -> xbuf overlay safe; lpx visible
#pragma unroll
    for (int rb = 0; rb < 2; ++rb)
        inv[rb] = __builtin_amdgcn_rcpf(lp[rb] + lpx[wave ^ 4][rb][l16]);

    // 4-phase merge over g = (ks,dir) into xbuf[pair]; g==0 stores.
    const int g = (ks << 1) | dir;
#pragma unroll 1
    for (int ph = 3; ph >= 1; --ph) {
        if (g == ph) {
#pragma unroll
            for (int rb = 0; rb < 2; ++rb)
#pragma unroll
                for (int ct = 0; ct < 4; ++ct)
#pragma unroll
                    for (int r = 0; r < 4; ++r) {
                        const int slot = (pair * 32 + rb * 16 + ct * 4 + r) * 64 + lane;
                        float v = accO[rb][ct][r] * inv[rb];
                        if (ph == 3) xbuf[slot] = v;
                        else xbuf[slot] += v;
                    }
        }
        __syncthreads();
    }
    if (g == 0) {
        float* ob = out + (size_t)b * plane;
#pragma unroll
        for (int rb = 0; rb < 2; ++rb)
#pragma unroll
            for (int ct = 0; ct < 4; ++ct)
#pragma unroll
                for (int r = 0; r < 4; ++r) {
                    float v = accO[rb][ct][r] * inv[rb] +
                              xbuf[(pair * 32 + rb * 16 + ct * 4 + r) * 64 + lane];
                    // out[c = ct*16+quad*4+r][t = q0+rb*16+l16]: coalesced over l16
                    ob[(size_t)(ct * 16 + quad * 4 + r) * TT + q0 + rb * 16 + l16] = v;
                }
    }
}

extern "C" void kernel_launch(void* const* d_in, const int* in_sizes, int n_in,
                              void* d_out, int out_size, void* d_ws, size_t ws_size,
                              hipStream_t stream) {
    const float* x1 = (const float*)d_in[0];
    const float* x2 = (const float*)d_in[1];
    ushort* xt = (ushort*)d_ws;                              // 8 MB
    ushort* vt = (ushort*)d_ws + (size_t)2 * NB * TT * CC;   // 8 MB

    hipLaunchKernelGGL(prep_k, dim3(TT / 64, NB, 2), dim3(256), 0, stream, x1, x2, xt, vt);
    hipLaunchKernelGGL(attn_fused_k, dim3(64 * NB), dim3(512), 0, stream,
                       xt, vt, (float*)d_out);
}

// Round 4
// 228.054 us; speedup vs baseline: 3.2048x; 1.5604x over previous
//
#include <hip/hip_runtime.h>
#include <hip/hip_bf16.h>
#include <stdint.h>

// MutualCrossAttention: B=8, C=64, H=W=64 -> T=4096 tokens. Inputs FP32, output FP32.
// dir A: Q=x1, K=V=x2 ; dir B: Q=x2, K=V=x1 ; out = outA + outB, layout [b][c][t].
// R16 = R15 (R12 skeleton + V reg-prefetch in 8 named s16x8) with the register
// budget FIXED: __launch_bounds__(512, 2). R14/R15 proved the allocator pinned
// VGPR_Count=64 under (512,4) and spilled the V prefetch to scratch
// (WRITE_SIZE 17MB -> 1.78GB/503MB). LDS (74.75KB) caps the kernel at 2 blk/CU
// = 4 waves/SIMD anyway, so raising the per-wave cap to 256 VGPRs costs zero
// occupancy and lets vpf/accO/qf/st all live in registers.
// Pipeline per iter: [B1] wrst + loadst(j+1) + PV(j-1) [B2] prefV(j) + S(j).
// prefV right after B2 -> whole Sphase covers the 8 c-major V loads (~300cy L2);
// PVphase is pure reg-MFMA and overlaps the staging drain in the B1 gap.
//   - S^T composition (A=K,B=Q then A=V,B=P^T) proved in R3-R5; P^T C/D layout
//     gives 4 consecutive tokens/lane -> b64 pbuf write, b128 read, stride-72.
//   - lp is one scalar per lane (q = l16 column), butterflied over quads.
//   - O^T epilogue: row=c, col=q -> scalar f32 stores coalesced over l16.
// ws: [0,8MB) xt bf16 token-major {x1,x2} PRE-SCALED by sqrt(log2(e)/8);
//     [8MB,16MB) vt bf16 c-major {x1,x2} unscaled.

#define TT 4096
#define CC 64
#define NB 8

typedef float f32x4 __attribute__((ext_vector_type(4)));
typedef float f32x4a __attribute__((ext_vector_type(4), may_alias));
typedef short s16x8 __attribute__((ext_vector_type(8)));
typedef unsigned int u32x2a __attribute__((ext_vector_type(2), may_alias));
typedef unsigned int u32x4a __attribute__((ext_vector_type(4), may_alias));
typedef float f32a __attribute__((may_alias));

static __device__ __forceinline__ unsigned fbits(float x) { return __float_as_uint(x); }
static __device__ __forceinline__ ushort bf16of(float v) {
    return (ushort)((fbits(v) + 0x8000u) >> 16);
}
static __device__ __forceinline__ unsigned pack2(float a, float b) {
    return __builtin_amdgcn_perm(fbits(b) + 0x8000u, fbits(a) + 0x8000u, 0x07060302u);
}
static __device__ __forceinline__ s16x8 load_frag(const void* p) {
    u32x4a t = *(const u32x4a*)p;
    return __builtin_bit_cast(s16x8, t);
}

#define SQC1 0.4246609177f  // sqrt(log2(e)/8), applied to xt on both Q and K sides

__global__ void prep_k(const float* __restrict__ x1, const float* __restrict__ x2,
                       ushort* __restrict__ xt, ushort* __restrict__ vt) {
    const int inp = blockIdx.z, b = blockIdx.y, t0 = blockIdx.x * 64;
    const float* src = (inp == 0 ? x1 : x2) + (size_t)b * CC * TT;
    const size_t plane = (size_t)TT * CC;
    ushort* xd = xt + (size_t)(inp * NB + b) * plane;
    ushort* vd = vt + (size_t)(inp * NB + b) * plane;
    __shared__ ushort lds[64][72];
    const int tid = threadIdx.x;
    const int c  = tid >> 2;
    const int tg = tid & 3;
    const float* srow = src + (size_t)c * TT + t0 + tg * 16;
    unsigned hw[8];
#pragma unroll
    for (int i = 0; i < 4; ++i) {
        f32x4a v = *(const f32x4a*)(srow + i * 4);
        hw[2 * i]     = pack2(v[0], v[1]);
        hw[2 * i + 1] = pack2(v[2], v[3]);
#pragma unroll
        for (int k = 0; k < 4; ++k) lds[tg * 16 + i * 4 + k][c] = bf16of(v[k] * SQC1);
    }
    ushort* vrow = vd + (size_t)c * TT + t0 + tg * 16;
    u32x4a w0 = {hw[0], hw[1], hw[2], hw[3]};
    u32x4a w1 = {hw[4], hw[5], hw[6], hw[7]};
    *(u32x4a*)(vrow) = w0;
    *(u32x4a*)(vrow + 8) = w1;
    __syncthreads();
#pragma unroll
    for (int pass = 0; pass < 2; ++pass) {
        const int t  = (tid >> 3) + pass * 32;
        const int c8 = (tid & 7) * 8;
        u32x4a w = *(const u32x4a*)&lds[t][c8];
        *(u32x4a*)(xd + (size_t)(t0 + t) * CC + c8) = w;
    }
}

// grid = 512 blocks (qt 0..63 x b 0..7), 512 threads = 8 waves.
// wave: dir = w&1, pair = (w>>1)&1, ks = w>>2 (2048-token half).
__global__ __launch_bounds__(512, 2)
void attn_fused_k(const ushort* __restrict__ xt, const ushort* __restrict__ vt,
                  float* __restrict__ out) {
    const int b    = blockIdx.x & 7;
    const int qt   = blockIdx.x >> 3;
    const int tid  = threadIdx.x;
    const int wave = tid >> 6;
    const int lane = tid & 63;
    const int quad = lane >> 4;
    const int l16  = lane & 15;
    const int dir  = wave & 1;
    const int pair = (wave >> 1) & 1;
    const int ks   = wave >> 2;
    const int q0   = qt * 64 + pair * 32;

    const size_t plane = (size_t)TT * CC;
    const ushort* Qb = xt + (size_t)((dir == 0 ? 0 : NB) + b) * plane;  // token-major
    const ushort* Vb = vt + (size_t)((dir == 0 ? NB : 0) + b) * plane;  // c-major

    __shared__ __align__(16) ushort ktile[4][64][72];      // 36.9 KB
    __shared__ __align__(16) ushort pbuf[8][2][16][72];    // 36.9 KB (q rows, tok cols)
    __shared__ float lpx[8][2][16];                        // 1 KB
    f32a* xbuf = (f32a*)&pbuf[0][0][0][0];                 // 16 KB overlay, post-loop

    // staging role: tile sub = (sk,sd); 4 x 16B chunks per thread.
    const int sub = tid >> 7;
    const int sk  = sub >> 1;
    const int sd  = sub & 1;
    const int ch0 = tid & 127;
    const ushort* Ksrc = xt + (size_t)((sd == 0 ? NB : 0) + b) * plane;
    u32x4a st[4];

    auto loadst = [&](int j) {
        const ushort* g = Ksrc + (size_t)(sk * 32 + j) * 64 * CC;
#pragma unroll
        for (int i = 0; i < 4; ++i)
            st[i] = *(const u32x4a*)(g + (size_t)(ch0 + i * 128) * 8);
    };
    auto wrst = [&]() {
        unsigned* d = (unsigned*)&ktile[sub][0][0];
#pragma unroll
        for (int i = 0; i < 4; ++i) {
            const int c = ch0 + i * 128;
            *(u32x4a*)&d[(c >> 3) * 36 + (c & 7) * 4] = st[i];
        }
    };

    // Q b-frags: B[n=q=l16][k=c=quad*8+j], pre-scaled.
    s16x8 qf[2][2];
#pragma unroll
    for (int rb = 0; rb < 2; ++rb)
#pragma unroll
        for (int ch = 0; ch < 2; ++ch)
            qf[rb][ch] = load_frag(Qb + (size_t)(q0 + rb * 16 + l16) * CC + ch * 32 + quad * 8);

    f32x4 accO[2][4];  // O^T partial: row=c=quad*4+r (+ct*16), col=q=l16 (+rb*16)
#pragma unroll
    for (int rb = 0; rb < 2; ++rb)
#pragma unroll
        for (int ct = 0; ct < 4; ++ct) accO[rb][ct] = (f32x4){0.f, 0.f, 0.f, 0.f};
    float lp[2] = {0.f, 0.f};

    const ushort* vp  = Vb + (size_t)l16 * TT + quad * 8;
    const ushort* kfb = &ktile[ks * 2 + dir][0][0];

    // V register prefetch for PV(j): EIGHT NAMED regs (vA* = ch2 0, vB* = ch2 1),
    // issued right after the 2nd barrier so Sphase covers the L2 latency.
    s16x8 vA0, vA1, vA2, vA3, vB0, vB1, vB2, vB3;
    auto prefV = [&](int j) {
        const ushort* p0 = vp + (size_t)(ks * 32 + j) * 64;
        vA0 = load_frag(p0 + (size_t)( 0) * TT);
        vA1 = load_frag(p0 + (size_t)(16) * TT);
        vA2 = load_frag(p0 + (size_t)(32) * TT);
        vA3 = load_frag(p0 + (size_t)(48) * TT);
        vB0 = load_frag(p0 + (size_t)( 0) * TT + 32);
        vB1 = load_frag(p0 + (size_t)(16) * TT + 32);
        vB2 = load_frag(p0 + (size_t)(32) * TT + 32);
        vB3 = load_frag(p0 + (size_t)(48) * TT + 32);
    };

    // S^T(j): A = K from staged ktile [m=tok=mt*16+l16][k=c], B = Q.
    // D[row=tok=quad*4+r (+mt*16)][col=q=l16] -> 4 consecutive tokens -> b64 P write.
    auto Sphase = [&]() {
#pragma unroll
        for (int mt = 0; mt < 4; ++mt) {
            const ushort* kr = kfb + (size_t)(mt * 16 + l16) * 72 + quad * 8;
            s16x8 kf0 = load_frag(kr);
            s16x8 kf1 = load_frag(kr + 32);
#pragma unroll
            for (int rb = 0; rb < 2; ++rb) {
                f32x4 s = (f32x4){0.f, 0.f, 0.f, 0.f};
                s = __builtin_amdgcn_mfma_f32_16x16x32_bf16(kf0, qf[rb][0], s, 0, 0, 0);
                s = __builtin_amdgcn_mfma_f32_16x16x32_bf16(kf1, qf[rb][1], s, 0, 0, 0);
                float p0 = __builtin_amdgcn_exp2f(s[0]);
                float p1 = __builtin_amdgcn_exp2f(s[1]);
                float p2 = __builtin_amdgcn_exp2f(s[2]);
                float p3 = __builtin_amdgcn_exp2f(s[3]);
                lp[rb] += (p0 + p1) + (p2 + p3);
                u32x2a w;
                w[0] = pack2(p0, p1);
                w[1] = pack2(p2, p3);
                *(u32x2a*)&pbuf[wave][rb][l16][mt * 16 + quad * 4] = w;
            }
        }
    };
    // PV(j): A = V (prefetched named regs) [m=c=l16(+ct*16)][k=tok],
    //        B = P^T [n=q=l16][k=tok] (b128 LDS). Pure reg-MFMA otherwise.
    auto PVphase = [&]() {
        s16x8 pf0a = load_frag(&pbuf[wave][0][l16][quad * 8]);
        s16x8 pf1a = load_frag(&pbuf[wave][1][l16][quad * 8]);
        accO[0][0] = __builtin_amdgcn_mfma_f32_16x16x32_bf16(vA0, pf0a, accO[0][0], 0, 0, 0);
        accO[1][0] = __builtin_amdgcn_mfma_f32_16x16x32_bf16(vA0, pf1a, accO[1][0], 0, 0, 0);
        accO[0][1] = __builtin_amdgcn_mfma_f32_16x16x32_bf16(vA1, pf0a, accO[0][1], 0, 0, 0);
        accO[1][1] = __builtin_amdgcn_mfma_f32_16x16x32_bf16(vA1, pf1a, accO[1][1], 0, 0, 0);
        accO[0][2] = __builtin_amdgcn_mfma_f32_16x16x32_bf16(vA2, pf0a, accO[0][2], 0, 0, 0);
        accO[1][2] = __builtin_amdgcn_mfma_f32_16x16x32_bf16(vA2, pf1a, accO[1][2], 0, 0, 0);
        accO[0][3] = __builtin_amdgcn_mfma_f32_16x16x32_bf16(vA3, pf0a, accO[0][3], 0, 0, 0);
        accO[1][3] = __builtin_amdgcn_mfma_f32_16x16x32_bf16(vA3, pf1a, accO[1][3], 0, 0, 0);
        s16x8 pf0b = load_frag(&pbuf[wave][0][l16][32 + quad * 8]);
        s16x8 pf1b = load_frag(&pbuf[wave][1][l16][32 + quad * 8]);
        accO[0][0] = __builtin_amdgcn_mfma_f32_16x16x32_bf16(vB0, pf0b, accO[0][0], 0, 0, 0);
        accO[1][0] = __builtin_amdgcn_mfma_f32_16x16x32_bf16(vB0, pf1b, accO[1][0], 0, 0, 0);
        accO[0][1] = __builtin_amdgcn_mfma_f32_16x16x32_bf16(vB1, pf0b, accO[0][1], 0, 0, 0);
        accO[1][1] = __builtin_amdgcn_mfma_f32_16x16x32_bf16(vB1, pf1b, accO[1][1], 0, 0, 0);
        accO[0][2] = __builtin_amdgcn_mfma_f32_16x16x32_bf16(vB2, pf0b, accO[0][2], 0, 0, 0);
        accO[1][2] = __builtin_amdgcn_mfma_f32_16x16x32_bf16(vB2, pf1b, accO[1][2], 0, 0, 0);
        accO[0][3] = __builtin_amdgcn_mfma_f32_16x16x32_bf16(vB3, pf0b, accO[0][3], 0, 0, 0);
        accO[1][3] = __builtin_amdgcn_mfma_f32_16x16x32_bf16(vB3, pf1b, accO[1][3], 0, 0, 0);
    };

    // Pipeline per iter: [B1] wrst + loadst(j+1) + PV(j-1) [B2] prefV(j) + S(j).
    // prefV right after B2 -> the whole Sphase covers the 8 V loads; at the next
    // B1, wrst waits only the 4 OLDER loadst loads (vmcnt(8)), and PV's first
    // MFMA waits vpf which has had Sphase + a barrier to complete.
    loadst(0);
    wrst();
    loadst(1);
    __syncthreads();
    prefV(0);
    Sphase();            // j = 0
#pragma unroll 1
    for (int j = 1; j < 32; ++j) {
        __syncthreads();           // B1: all waves done reading ktile(j-1)
        wrst();                    // write ktile(j)
        if (j < 31) loadst(j + 1);
        PVphase();                 // PV(j-1): pure reg-MFMA, overlaps staging drain
        __syncthreads();           // B2: ktile(j) visible
        prefV(j);                  // V(j) loads covered by Sphase(j)
        Sphase();                  // S(j), overwrites pbuf AFTER PV consumed it
    }
    PVphase();           // PV(31)

    // Denominator: quads hold disjoint token subsets for col q=l16.
    float inv[2];
#pragma unroll
    for (int rb = 0; rb < 2; ++rb) {
        float l = lp[rb];
        l += __shfl_xor(l, 16);
        l += __shfl_xor(l, 32);
        lp[rb] = l;
        if (lane < 16) lpx[wave][rb][l16] = l;
    }
    __syncthreads();  // pbuf dead -> xbuf overlay safe; lpx visible
#pragma unroll
    for (int rb = 0; rb < 2; ++rb)
        inv[rb] = __builtin_amdgcn_rcpf(lp[rb] + lpx[wave ^ 4][rb][l16]);

    // 4-phase merge over g = (ks,dir) into xbuf[pair]; g==0 stores.
    const int g = (ks << 1) | dir;
#pragma unroll 1
    for (int ph = 3; ph >= 1; --ph) {
        if (g == ph) {
#pragma unroll
            for (int rb = 0; rb < 2; ++rb)
#pragma unroll
                for (int ct = 0; ct < 4; ++ct)
#pragma unroll
                    for (int r = 0; r < 4; ++r) {
                        const int slot = (pair * 32 + rb * 16 + ct * 4 + r) * 64 + lane;
                        float v = accO[rb][ct][r] * inv[rb];
                        if (ph == 3) xbuf[slot] = v;
                        else xbuf[slot] += v;
                    }
        }
        __syncthreads();
    }
    if (g == 0) {
        float* ob = out + (size_t)b * plane;
#pragma unroll
        for (int rb = 0; rb < 2; ++rb)
#pragma unroll
            for (int ct = 0; ct < 4; ++ct)
#pragma unroll
                for (int r = 0; r < 4; ++r) {
                    float v = accO[rb][ct][r] * inv[rb] +
                              xbuf[(pair * 32 + rb * 16 + ct * 4 + r) * 64 + lane];
                    // out[c = ct*16+quad*4+r][t = q0+rb*16+l16]: coalesced over l16
                    ob[(size_t)(ct * 16 + quad * 4 + r) * TT + q0 + rb * 16 + l16] = v;
                }
    }
}

extern "C" void kernel_launch(void* const* d_in, const int* in_sizes, int n_in,
                              void* d_out, int out_size, void* d_ws, size_t ws_size,
                              hipStream_t stream) {
    const float* x1 = (const float*)d_in[0];
    const float* x2 = (const float*)d_in[1];
    ushort* xt = (ushort*)d_ws;                              // 8 MB
    ushort* vt = (ushort*)d_ws + (size_t)2 * NB * TT * CC;   // 8 MB

    hipLaunchKernelGGL(prep_k, dim3(TT / 64, NB, 2), dim3(256), 0, stream, x1, x2, xt, vt);
    hipLaunchKernelGGL(attn_fused_k, dim3(64 * NB), dim3(512), 0, stream,
                       xt, vt, (float*)d_out);
}